// Round 8
// baseline (194.999 us; speedup 1.0000x reference)
//
#include <hip/hip_runtime.h>
#include <hip/hip_bf16.h>
#include <stdint.h>

// Problem constants: B=2, T=2048, D=1024, H=16, HD=64
#define B_  2
#define T_  2048
#define D_  1024
#define H_  16
#define HD_ 64

typedef __bf16 bf16x8 __attribute__((ext_vector_type(8)));
typedef __bf16 bf16x4 __attribute__((ext_vector_type(4)));
typedef float  f32x4  __attribute__((ext_vector_type(4)));
typedef short  s16x4  __attribute__((ext_vector_type(4)));

__device__ __forceinline__ void async_copy16(const void* g, void* l) {
  __builtin_amdgcn_global_load_lds((__attribute__((address_space(1))) void*)(g),
                                   (__attribute__((address_space(3))) void*)(l),
                                   16, 0, 0);
}

// ---------------------------------------------------------------------------
// Fused prep (fp32 inputs hardcoded — proven R3-R9):
//   blocks [0,4096):    transpose+convert the four 1024x1024 fp32 weights to
//                       bf16, dst[n][k]=src[k][n] (wq,wk,wv->wqkv_t; wo->wo_t)
//   blocks [4096,8192): convert x fp32 -> bf16 (4 elems/thread, f32x4 loads)
// ---------------------------------------------------------------------------
__global__ void prep_kernel(const float* __restrict__ x,
                            const float* __restrict__ wq, const float* __restrict__ wk,
                            const float* __restrict__ wv, const float* __restrict__ wo,
                            __bf16* __restrict__ xc,
                            __bf16* __restrict__ wqkv_t, __bf16* __restrict__ wo_t) {
  const int id  = blockIdx.x;
  const int tid = threadIdx.x;
  if (id < 4096) {
    __shared__ __bf16 tile[32][33];
    const int z   = id >> 10;
    const int rem = id & 1023;
    const int n0 = (rem & 31) * 32, k0 = (rem >> 5) * 32;
    const int tx = tid & 31, ty = tid >> 5;
    const float* src = (z == 0) ? wq : (z == 1) ? wk : (z == 2) ? wv : wo;
    __bf16* dst = (z < 3) ? (wqkv_t + (size_t)z * 1024 * 1024) : wo_t;
#pragma unroll
    for (int i = 0; i < 4; ++i)
      tile[ty + 8 * i][tx] = (__bf16)src[(size_t)(k0 + ty + 8 * i) * 1024 + n0 + tx];
    __syncthreads();
#pragma unroll
    for (int i = 0; i < 4; ++i)
      dst[(size_t)(n0 + ty + 8 * i) * 1024 + k0 + tx] = tile[tx][ty + 8 * i];
  } else {
    const int i0 = ((id - 4096) * 256 + tid) * 4;
    const f32x4 f = *(const f32x4*)(x + i0);       // 16B vector load (G13)
    bf16x4 v;
#pragma unroll
    for (int k = 0; k < 4; ++k) v[k] = (__bf16)f[k];
    *(bf16x4*)(xc + i0) = v;
  }
}

// ---------------------------------------------------------------------------
// 128x128-tile bf16 MFMA GEMM, async global_load_lds staging — PROVEN (R5,
// measured in the 172.6us total). T1 XCD-aware bijective grid swizzle.
// MODE 0 epilogue scatters Q (x0.125) / K to [b,h,t,hd], V^T to [b,h,hd,t].
// MODE 1 epilogue adds bias (fp32), stores fp32 to out.
// ---------------------------------------------------------------------------
template <int MODE>
__launch_bounds__(256)
__global__ void gemm128_kernel(const __bf16* __restrict__ A, const __bf16* __restrict__ Bt, int K,
                               __bf16* __restrict__ q_b, __bf16* __restrict__ k_b,
                               __bf16* __restrict__ vt_b,
                               const float* __restrict__ bo, float* __restrict__ outp) {
  __shared__ __align__(16) __bf16 As[128 * 64];
  __shared__ __align__(16) __bf16 Bs[128 * 64];
  const int tid  = threadIdx.x;
  const int w    = tid >> 6, lane = tid & 63;
  const int quad = lane >> 4, lr = lane & 15;

  const int orig = blockIdx.x;
  int bx, by;
  if (MODE == 0) {
    const int wgid = (orig & 7) * 96 + (orig >> 3);   // 768 blocks
    bx = wgid >> 5;            // 0..23  (N columns, 3 per XCD)
    by = wgid & 31;            // 0..31
  } else {
    const int wgid = (orig & 7) * 32 + (orig >> 3);   // 256 blocks
    bx = wgid & 7;             // 0..7
    by = wgid >> 3;            // 0..31
  }
  const int tm = by * 128, tn = bx * 128;
  const int wm = (w >> 1) * 64, wn = (w & 1) * 64;
  const int lrow   = lane >> 3;
  const int gchunk = (lane & 7) ^ lrow;

  f32x4 acc[4][4] = {};

  for (int k0 = 0; k0 < K; k0 += 64) {
#pragma unroll
    for (int c = 0; c < 4; ++c) {
      const int chunk = w * 4 + c;             // wave-uniform LDS base
      const int row   = chunk * 8 + lrow;
      async_copy16(A  + (size_t)(tm + row) * K + k0 + gchunk * 8, As + chunk * 512);
      async_copy16(Bt + (size_t)(tn + row) * K + k0 + gchunk * 8, Bs + chunk * 512);
    }
    __syncthreads();
#pragma unroll
    for (int ks = 0; ks < 2; ++ks) {
      bf16x8 af[4], bfr[4];
#pragma unroll
      for (int mi = 0; mi < 4; ++mi) {
        const int row = wm + mi * 16 + lr;
        const int ch  = (ks * 4 + quad) ^ (row & 7);
        af[mi] = *(const bf16x8*)(As + row * 64 + ch * 8);
      }
#pragma unroll
      for (int ni = 0; ni < 4; ++ni) {
        const int row = wn + ni * 16 + lr;
        const int ch  = (ks * 4 + quad) ^ (row & 7);
        bfr[ni] = *(const bf16x8*)(Bs + row * 64 + ch * 8);
      }
#pragma unroll
      for (int mi = 0; mi < 4; ++mi)
#pragma unroll
        for (int ni = 0; ni < 4; ++ni)
          acc[mi][ni] = __builtin_amdgcn_mfma_f32_16x16x32_bf16(af[mi], bfr[ni], acc[mi][ni], 0, 0, 0);
    }
    __syncthreads();
  }

  if (MODE == 0) {
#pragma unroll
    for (int mi = 0; mi < 4; ++mi) {
      const int mrow0 = tm + wm + mi * 16 + quad * 4;
      const int b  = mrow0 >> 11;
      const int t0 = mrow0 & 2047;
#pragma unroll
      for (int ni = 0; ni < 4; ++ni) {
        const int ncol = tn + wn + ni * 16 + lr;
        const int mat  = ncol >> 10;
        const int nn   = ncol & 1023;
        const int h = nn >> 6, hd = nn & 63;
        if (mat == 0) {
#pragma unroll
          for (int r = 0; r < 4; ++r)
            q_b[((size_t)((b * H_ + h) * T_ + t0 + r)) * HD_ + hd] =
                (__bf16)(acc[mi][ni][r] * 0.125f);
        } else if (mat == 1) {
#pragma unroll
          for (int r = 0; r < 4; ++r)
            k_b[((size_t)((b * H_ + h) * T_ + t0 + r)) * HD_ + hd] =
                (__bf16)(acc[mi][ni][r]);
        } else {
          bf16x4 pk;
#pragma unroll
          for (int r = 0; r < 4; ++r) pk[r] = (__bf16)(acc[mi][ni][r]);
          *(bf16x4*)(vt_b + ((size_t)(b * H_ + h) * HD_ + hd) * T_ + t0) = pk;
        }
      }
    }
  } else {
#pragma unroll
    for (int mi = 0; mi < 4; ++mi) {
      const int m0 = tm + wm + mi * 16 + quad * 4;
#pragma unroll
      for (int ni = 0; ni < 4; ++ni) {
        const int n = tn + wn + ni * 16 + lr;
        const float bias = bo[n];
#pragma unroll
        for (int r = 0; r < 4; ++r)
          outp[(size_t)(m0 + r) * D_ + n] = acc[mi][ni][r] + bias;
      }
    }
  }
}

// ---------------------------------------------------------------------------
// Flash attention v13 (causal): BARRIER-FREE main loop.
// R7 diagnosis: nothing >30% busy -> bound by the inter-wave P exchange chain
// (QK -> exp -> LDS -> PV under 3 barriers/tile). v13 removes the exchange:
//  - Wave w owns kv-slice [j*64+w*16, +16) of EVERY tile j, for ALL 64 q.
//  - Swapped QK^T (16x16x32, v11-proven): lane (quad,lr) holds
//    P^T[kv=quad*4+r][q=lr] — which IS the B-operand fragment of a
//    16x16x16 MFMA (B[col=lr][k=quad*4+i]). So PV partials accumulate
//    directly: ot[hb][qb] += mfma_16x16x16(vf[hb], pb[qb]) where vf is
//    V^T loaded straight from global (b64, layout-exact). P stays in
//    registers; K and V never touch LDS; ZERO barriers in the loop.
//  - Row sums: ls[qb] += mfma_16x16x16(ones, pb[qb]) — same C-layout.
//  - Per block, ONE LDS combine at the end sums the 4 waves' partial
//    O^T[hd][q] (f32, sO pitch 68 for bank spread) + ls, normalizes, stores.
// K/V global traffic per tile unchanged vs staged (each slice read once).
// 2-deep named-register prefetch (no dynamic reg indexing — rule #20).
// Grid 1024 + heavy-first balanced map + XCD head clustering unchanged.
// ---------------------------------------------------------------------------
__launch_bounds__(256, 2)
__global__ void attn_kernel(const __bf16* __restrict__ q_b, const __bf16* __restrict__ k_b,
                            const __bf16* __restrict__ vt_b, __bf16* __restrict__ ctx) {
  __shared__ __align__(16) float sO[4][64][68];   // [w][q][hd] pitch 68
  __shared__ float sLS[4][64];                    // [w][q]
  const int tid  = threadIdx.x;
  const int w    = tid >> 6, lane = tid & 63;
  const int quad = lane >> 4, lr = lane & 15;
  const int id = blockIdx.x;
  const int bh  = (id & 7) * 4 + ((id >> 3) & 3);   // XCD-clustered head
  const int t0i = (id >> 5) & 7;                    // slot within round
  const int rnd = id >> 8;                          // round 0..3 (heavy first)
  const int tq  = (3 - rnd) * 8 + ((rnd & 1) ? t0i : (7 - t0i));
  const __bf16* qh = q_b  + (size_t)bh * T_ * HD_;
  const __bf16* kh = k_b  + (size_t)bh * T_ * HD_;
  const __bf16* vh = vt_b + (size_t)bh * HD_ * T_;
  const int b = bh >> 4, h = bh & 15;

  const int q0 = tq * 64;
  const int nj = tq + 1;
  const int w16 = w * 16;

  // Q B-fragments for all 4 q-subtiles (loop-invariant, 32 VGPR)
  bf16x8 qf[4][2];
#pragma unroll
  for (int qs = 0; qs < 4; ++qs)
#pragma unroll
    for (int ks = 0; ks < 2; ++ks)
      qf[qs][ks] = *(const bf16x8*)(qh + (size_t)(q0 + qs * 16 + lr) * HD_ + ks * 32 + quad * 8);

  const s16x4 ones16 = {0x3F80, 0x3F80, 0x3F80, 0x3F80};  // bf16 1.0 x4

  f32x4 ot[4][4] = {};   // [hb][qb] partial O^T: hd=hb*16+quad*4+r, q=qb*16+lr
  f32x4 lsa[4]   = {};   // [qb] partial rowsum, q=qb*16+lr (replicated)

  // per-wave global bases (lane-resolved)
  const __bf16* kbase = kh + (size_t)(w16 + lr) * HD_ + quad * 8;
  const __bf16* vbase = vh + (size_t)lr * T_ + w16 + quad * 4;

  auto LK = [&](int j, bf16x8& k0, bf16x8& k1) {
    const __bf16* p = kbase + (size_t)j * 64 * HD_;
    k0 = *(const bf16x8*)p;
    k1 = *(const bf16x8*)(p + 32);
  };
  auto LV = [&](int j, s16x4& v0, s16x4& v1, s16x4& v2, s16x4& v3) {
    const __bf16* p = vbase + j * 64;
    v0 = *(const s16x4*)(p);
    v1 = *(const s16x4*)(p + 16 * T_);
    v2 = *(const s16x4*)(p + 32 * T_);
    v3 = *(const s16x4*)(p + 48 * T_);
  };

  auto TILE = [&](int j, const bf16x8& k0, const bf16x8& k1,
                  const s16x4& v0, const s16x4& v1, const s16x4& v2, const s16x4& v3) {
    // S^T = K (Q/8)^T for this wave's 16 kv x all 64 q (8 MFMA, k=32)
    f32x4 ns[4] = {};
    __builtin_amdgcn_s_setprio(1);
#pragma unroll
    for (int qb = 0; qb < 4; ++qb) {
      ns[qb] = __builtin_amdgcn_mfma_f32_16x16x32_bf16(k0, qf[qb][0], ns[qb], 0, 0, 0);
      ns[qb] = __builtin_amdgcn_mfma_f32_16x16x32_bf16(k1, qf[qb][1], ns[qb], 0, 0, 0);
    }
    __builtin_amdgcn_s_setprio(0);
    // causal mask (diagonal tile only): kv=j0+w16+quad*4+r, q=q0+qb*16+lr
    if (j == nj - 1) {
      const int kvb = j * 64 + w16 + quad * 4;
#pragma unroll
      for (int qb = 0; qb < 4; ++qb) {
        const int qg = q0 + qb * 16 + lr;
#pragma unroll
        for (int r = 0; r < 4; ++r)
          if (kvb + r > qg) ns[qb][r] = -3.0e38f;
      }
    }
    // static-base softmax P = exp(s); pack to bf16 B-fragments (lane-local!)
    s16x4 pb[4];
#pragma unroll
    for (int qb = 0; qb < 4; ++qb) {
      bf16x4 t;
#pragma unroll
      for (int r = 0; r < 4; ++r) t[r] = (__bf16)__expf(ns[qb][r]);
      pb[qb] = __builtin_bit_cast(s16x4, t);
    }
    // partial O^T += V^T x P  (16 MFMA, k=16) + rowsums (4 MFMA)
    const s16x4 vv[4] = {v0, v1, v2, v3};
    __builtin_amdgcn_s_setprio(1);
#pragma unroll
    for (int hb = 0; hb < 4; ++hb)
#pragma unroll
      for (int qb = 0; qb < 4; ++qb)
        ot[hb][qb] = __builtin_amdgcn_mfma_f32_16x16x16bf16_1k(vv[hb], pb[qb], ot[hb][qb], 0, 0, 0);
#pragma unroll
    for (int qb = 0; qb < 4; ++qb)
      lsa[qb] = __builtin_amdgcn_mfma_f32_16x16x16bf16_1k(ones16, pb[qb], lsa[qb], 0, 0, 0);
    __builtin_amdgcn_s_setprio(0);
  };

  // streaming loop, 2-deep ping-pong prefetch, NO barriers
  bf16x8 ka0, ka1, kb0, kb1;
  s16x4  va0, va1, va2, va3, vb0, vb1, vb2, vb3;
  LK(0, ka0, ka1);
  LV(0, va0, va1, va2, va3);
  for (int j = 0; j < nj; ) {
    if (j + 1 < nj) { LK(j + 1, kb0, kb1); LV(j + 1, vb0, vb1, vb2, vb3); }
    TILE(j, ka0, ka1, va0, va1, va2, va3);
    ++j; if (j >= nj) break;
    if (j + 1 < nj) { LK(j + 1, ka0, ka1); LV(j + 1, va0, va1, va2, va3); }
    TILE(j, kb0, kb1, vb0, vb1, vb2, vb3);
    ++j;
  }

  // ---- combine: sum 4 waves' partials via LDS (the block's ONLY barrier) --
#pragma unroll
  for (int hb = 0; hb < 4; ++hb)
#pragma unroll
    for (int qb = 0; qb < 4; ++qb)
      *(f32x4*)&sO[w][qb * 16 + lr][hb * 16 + quad * 4] = ot[hb][qb];
  if (quad == 0) {
#pragma unroll
    for (int qb = 0; qb < 4; ++qb)
      sLS[w][qb * 16 + lr] = lsa[qb][0];
  }
  __syncthreads();
  // wave w finalizes q rows [w16, w16+16): lane (quad,lr) -> q=w16+lr,
  // hd = hb*16+quad*4 .. +3
  const float lsq = sLS[0][w16 + lr] + sLS[1][w16 + lr]
                  + sLS[2][w16 + lr] + sLS[3][w16 + lr];
  const float inv = 1.0f / lsq;
  const int t = q0 + w16 + lr;
#pragma unroll
  for (int hb = 0; hb < 4; ++hb) {
    f32x4 of = *(const f32x4*)&sO[0][w16 + lr][hb * 16 + quad * 4];
#pragma unroll
    for (int ww = 1; ww < 4; ++ww) {
      const f32x4 pv = *(const f32x4*)&sO[ww][w16 + lr][hb * 16 + quad * 4];
#pragma unroll
      for (int r = 0; r < 4; ++r) of[r] += pv[r];
    }
    bf16x4 pk;
#pragma unroll
    for (int r = 0; r < 4; ++r) pk[r] = (__bf16)(of[r] * inv);
    *(bf16x4*)(ctx + ((size_t)(b * T_ + t)) * D_ + h * HD_ + hb * 16 + quad * 4) = pk;
  }
}

// ---------------------------------------------------------------------------
extern "C" void kernel_launch(void* const* d_in, const int* in_sizes, int n_in,
                              void* d_out, int out_size, void* d_ws, size_t ws_size,
                              hipStream_t stream) {
  (void)in_sizes; (void)n_in; (void)out_size; (void)ws_size;
  const float* x  = (const float*)d_in[0];
  const float* wq = (const float*)d_in[1];
  const float* wk = (const float*)d_in[2];
  const float* wv = (const float*)d_in[3];
  const float* wo = (const float*)d_in[4];
  const float* bo = (const float*)d_in[5];
  float* outp = (float*)d_out;

  char* ws = (char*)d_ws;
  __bf16* ctx    = (__bf16*)(ws + 0);           // [4096][1024] = 8 MB
  __bf16* wqkv_t = (__bf16*)(ws + 0);           // 3072x1024 = 6 MB (dead after gemm<0>)
  __bf16* wo_t   = (__bf16*)(ws + 8388608);     // 1024x1024 = 2 MB
  __bf16* q_b    = (__bf16*)(ws + 10485760);    // [2][16][2048][64] = 8 MB
  __bf16* k_b    = (__bf16*)(ws + 18874368);    // 8 MB
  __bf16* vt_b   = (__bf16*)(ws + 27262976);    // [2][16][64][2048] = 8 MB
  __bf16* xc     = (__bf16*)(ws + 35651584);    // canonical bf16 x = 8 MB

  prep_kernel<<<8192, 256, 0, stream>>>(x, wq, wk, wv, wo, xc, wqkv_t, wo_t);
  gemm128_kernel<0><<<768, 256, 0, stream>>>(xc, wqkv_t, 1024, q_b, k_b, vt_b, nullptr, nullptr);
  attn_kernel<<<1024, 256, 0, stream>>>(q_b, k_b, vt_b, ctx);
  gemm128_kernel<1><<<256, 256, 0, stream>>>(ctx, wo_t, 1024, nullptr, nullptr, nullptr, bo, outp);
}

// Round 9
// 173.440 us; speedup vs baseline: 1.1243x; 1.1243x over previous
//
#include <hip/hip_runtime.h>
#include <hip/hip_bf16.h>
#include <stdint.h>

// Problem constants: B=2, T=2048, D=1024, H=16, HD=64
#define B_  2
#define T_  2048
#define D_  1024
#define H_  16
#define HD_ 64

typedef __bf16 bf16x8 __attribute__((ext_vector_type(8)));
typedef __bf16 bf16x4 __attribute__((ext_vector_type(4)));
typedef float  f32x4  __attribute__((ext_vector_type(4)));

__device__ __forceinline__ void async_copy16(const void* g, void* l) {
  __builtin_amdgcn_global_load_lds((__attribute__((address_space(1))) void*)(g),
                                   (__attribute__((address_space(3))) void*)(l),
                                   16, 0, 0);
}

// ---------------------------------------------------------------------------
// Fused prep (fp32 inputs hardcoded — proven R3-R9):
//   blocks [0,4096):    transpose+convert the four 1024x1024 fp32 weights to
//                       bf16, dst[n][k]=src[k][n] (wq,wk,wv->wqkv_t; wo->wo_t)
//   blocks [4096,8192): convert x fp32 -> bf16 (4 elems/thread, f32x4 loads)
// ---------------------------------------------------------------------------
__global__ void prep_kernel(const float* __restrict__ x,
                            const float* __restrict__ wq, const float* __restrict__ wk,
                            const float* __restrict__ wv, const float* __restrict__ wo,
                            __bf16* __restrict__ xc,
                            __bf16* __restrict__ wqkv_t, __bf16* __restrict__ wo_t) {
  const int id  = blockIdx.x;
  const int tid = threadIdx.x;
  if (id < 4096) {
    __shared__ __bf16 tile[32][33];
    const int z   = id >> 10;
    const int rem = id & 1023;
    const int n0 = (rem & 31) * 32, k0 = (rem >> 5) * 32;
    const int tx = tid & 31, ty = tid >> 5;
    const float* src = (z == 0) ? wq : (z == 1) ? wk : (z == 2) ? wv : wo;
    __bf16* dst = (z < 3) ? (wqkv_t + (size_t)z * 1024 * 1024) : wo_t;
#pragma unroll
    for (int i = 0; i < 4; ++i)
      tile[ty + 8 * i][tx] = (__bf16)src[(size_t)(k0 + ty + 8 * i) * 1024 + n0 + tx];
    __syncthreads();
#pragma unroll
    for (int i = 0; i < 4; ++i)
      dst[(size_t)(n0 + ty + 8 * i) * 1024 + k0 + tx] = tile[tx][ty + 8 * i];
  } else {
    const int i0 = ((id - 4096) * 256 + tid) * 4;
    const f32x4 f = *(const f32x4*)(x + i0);       // 16B vector load (G13)
    bf16x4 v;
#pragma unroll
    for (int k = 0; k < 4; ++k) v[k] = (__bf16)f[k];
    *(bf16x4*)(xc + i0) = v;
  }
}

// ---------------------------------------------------------------------------
// 128x128-tile bf16 MFMA GEMM, async global_load_lds staging — PROVEN (R5,
// in the 172.26us best total). T1 XCD-aware bijective grid swizzle:
//   MODE 0: grid 768; each XCD owns 3 full B-panel columns (768KB < 4MB L2).
//   MODE 1: grid 256; each XCD sees full wo_t (2MB) + A chunk.
// MODE 0 epilogue scatters Q (x0.125) / K to [b,h,t,hd], V^T to [b,h,hd,t].
// MODE 1 epilogue adds bias (fp32), stores fp32 to out.
// ---------------------------------------------------------------------------
template <int MODE>
__launch_bounds__(256)
__global__ void gemm128_kernel(const __bf16* __restrict__ A, const __bf16* __restrict__ Bt, int K,
                               __bf16* __restrict__ q_b, __bf16* __restrict__ k_b,
                               __bf16* __restrict__ vt_b,
                               const float* __restrict__ bo, float* __restrict__ outp) {
  __shared__ __align__(16) __bf16 As[128 * 64];
  __shared__ __align__(16) __bf16 Bs[128 * 64];
  const int tid  = threadIdx.x;
  const int w    = tid >> 6, lane = tid & 63;
  const int quad = lane >> 4, lr = lane & 15;

  const int orig = blockIdx.x;
  int bx, by;
  if (MODE == 0) {
    const int wgid = (orig & 7) * 96 + (orig >> 3);   // 768 blocks
    bx = wgid >> 5;            // 0..23  (N columns, 3 per XCD)
    by = wgid & 31;            // 0..31
  } else {
    const int wgid = (orig & 7) * 32 + (orig >> 3);   // 256 blocks
    bx = wgid & 7;             // 0..7
    by = wgid >> 3;            // 0..31
  }
  const int tm = by * 128, tn = bx * 128;
  const int wm = (w >> 1) * 64, wn = (w & 1) * 64;
  const int lrow   = lane >> 3;
  const int gchunk = (lane & 7) ^ lrow;

  f32x4 acc[4][4] = {};

  for (int k0 = 0; k0 < K; k0 += 64) {
#pragma unroll
    for (int c = 0; c < 4; ++c) {
      const int chunk = w * 4 + c;             // wave-uniform LDS base
      const int row   = chunk * 8 + lrow;
      async_copy16(A  + (size_t)(tm + row) * K + k0 + gchunk * 8, As + chunk * 512);
      async_copy16(Bt + (size_t)(tn + row) * K + k0 + gchunk * 8, Bs + chunk * 512);
    }
    __syncthreads();
#pragma unroll
    for (int ks = 0; ks < 2; ++ks) {
      bf16x8 af[4], bfr[4];
#pragma unroll
      for (int mi = 0; mi < 4; ++mi) {
        const int row = wm + mi * 16 + lr;
        const int ch  = (ks * 4 + quad) ^ (row & 7);
        af[mi] = *(const bf16x8*)(As + row * 64 + ch * 8);
      }
#pragma unroll
      for (int ni = 0; ni < 4; ++ni) {
        const int row = wn + ni * 16 + lr;
        const int ch  = (ks * 4 + quad) ^ (row & 7);
        bfr[ni] = *(const bf16x8*)(Bs + row * 64 + ch * 8);
      }
#pragma unroll
      for (int mi = 0; mi < 4; ++mi)
#pragma unroll
        for (int ni = 0; ni < 4; ++ni)
          acc[mi][ni] = __builtin_amdgcn_mfma_f32_16x16x32_bf16(af[mi], bfr[ni], acc[mi][ni], 0, 0, 0);
    }
    __syncthreads();
  }

  if (MODE == 0) {
#pragma unroll
    for (int mi = 0; mi < 4; ++mi) {
      const int mrow0 = tm + wm + mi * 16 + quad * 4;
      const int b  = mrow0 >> 11;
      const int t0 = mrow0 & 2047;
#pragma unroll
      for (int ni = 0; ni < 4; ++ni) {
        const int ncol = tn + wn + ni * 16 + lr;
        const int mat  = ncol >> 10;
        const int nn   = ncol & 1023;
        const int h = nn >> 6, hd = nn & 63;
        if (mat == 0) {
#pragma unroll
          for (int r = 0; r < 4; ++r)
            q_b[((size_t)((b * H_ + h) * T_ + t0 + r)) * HD_ + hd] =
                (__bf16)(acc[mi][ni][r] * 0.125f);
        } else if (mat == 1) {
#pragma unroll
          for (int r = 0; r < 4; ++r)
            k_b[((size_t)((b * H_ + h) * T_ + t0 + r)) * HD_ + hd] =
                (__bf16)(acc[mi][ni][r]);
        } else {
          bf16x4 pk;
#pragma unroll
          for (int r = 0; r < 4; ++r) pk[r] = (__bf16)(acc[mi][ni][r]);
          *(bf16x4*)(vt_b + ((size_t)(b * H_ + h) * HD_ + hd) * T_ + t0) = pk;
        }
      }
    }
  } else {
#pragma unroll
    for (int mi = 0; mi < 4; ++mi) {
      const int m0 = tm + wm + mi * 16 + quad * 4;
#pragma unroll
      for (int ni = 0; ni < 4; ++ni) {
        const int n = tn + wn + ni * 16 + lr;
        const float bias = bo[n];
#pragma unroll
        for (int r = 0; r < 4; ++r)
          outp[(size_t)(m0 + r) * D_ + n] = acc[mi][ni][r] + bias;
      }
    }
  }
}

// ---------------------------------------------------------------------------
// Flash attention v11 (causal) — EXACT R6 code (best measured total 172.26us),
// with ONE change: __launch_bounds__(256,3) -> (256,4).
// Rationale (R8 post-mortem): three structural rewrites (v12 one-barrier,
// v13 barrier-free k16-PV) all regressed vs v11; the only measured-positive
// attn lever was occupancy (R0->R1, 52->43us). v11 uses 80 VGPR / 34KB LDS:
// both fit 4 blocks/CU (LDS 139KB<160KB; VGPR cap 128 at 4 waves/SIMD, no
// spill). Bonus: the R1 balanced tile map was DESIGNED for 4 resident
// blocks/CU (iterations sum to exactly 66 per CU) — exact at occupancy 4.
// Structure: K-split QK^T (wave w owns keys w*16..+15, swapped-operand MFMA
// S^T), K direct-to-reg ping-pong, V staged in XOR-swizzled LDS, block-shared
// sP[2] P^T exchange with b64 writes, ones-MFMA row sums, XCD head clustering.
// ---------------------------------------------------------------------------
__launch_bounds__(256, 4)
__global__ void attn_kernel(const __bf16* __restrict__ q_b, const __bf16* __restrict__ k_b,
                            const __bf16* __restrict__ vt_b, __bf16* __restrict__ ctx) {
  __shared__ __align__(16) __bf16 sV[64 * 64];      // [hd][kv] XOR-swizzled
  __shared__ __align__(16) __bf16 sP[2][64][72];    // block-shared dbuf P^T tile
  const int tid  = threadIdx.x;
  const int w    = tid >> 6, lane = tid & 63;
  const int quad = lane >> 4, lr = lane & 15;
  const int id = blockIdx.x;
  const int bh  = (id & 7) * 4 + ((id >> 3) & 3);   // XCD-clustered head
  const int t0i = (id >> 5) & 7;                    // slot within round
  const int rnd = id >> 8;                          // round 0..3 (heavy first)
  const int tq  = (3 - rnd) * 8 + ((rnd & 1) ? t0i : (7 - t0i));
  const __bf16* qh = q_b  + (size_t)bh * T_ * HD_;
  const __bf16* kh = k_b  + (size_t)bh * T_ * HD_;
  const __bf16* vh = vt_b + (size_t)bh * HD_ * T_;
  const int b = bh >> 4, h = bh & 15;

  const int r0 = tid >> 3, r1 = (tid + 256) >> 3;   // V staging rows (0..63)
  const int g0 = tid & 7;                           // chunk-in-row

  const int q0 = tq * 64;                           // block's 64-row Q tile
  const int nj = tq + 1;
  const int w16 = w * 16;

  bf16x8 qf[4][2];
#pragma unroll
  for (int qs = 0; qs < 4; ++qs)
#pragma unroll
    for (int ks = 0; ks < 2; ++ks)
      qf[qs][ks] = *(const bf16x8*)(qh + (size_t)(q0 + qs * 16 + lr) * HD_ + ks * 32 + quad * 8);

  bf16x8 onesf;
#pragma unroll
  for (int j = 0; j < 8; ++j) onesf[j] = (__bf16)1.0f;

  f32x4 o[4] = {};
  f32x4 ls = {};

  // K slice for this wave, iter 0 (direct to regs; ping-pong prefetched)
  const __bf16* kr = kh + (size_t)(w16 + lr) * HD_;
  bf16x8 kf0 = *(const bf16x8*)(kr + quad * 8);
  bf16x8 kf1 = *(const bf16x8*)(kr + 32 + quad * 8);
  bf16x8 kn0, kn1;

  // V tile j=0 prefetch into registers
  bf16x8 vr0 = *(const bf16x8*)(vh + (size_t)r0 * T_ + g0 * 8);
  bf16x8 vr1 = *(const bf16x8*)(vh + (size_t)r1 * T_ + g0 * 8);

  for (int j = 0; j < nj; ++j) {
    const int j0 = j * 64;
    const int pb = j & 1;
    __syncthreads();   // all waves done reading sV (and sP[pb]) from prev
    *(bf16x8*)(sV + r0 * 64 + (g0 ^ (r0 & 7)) * 8) = vr0;
    *(bf16x8*)(sV + r1 * 64 + (g0 ^ (r1 & 7)) * 8) = vr1;
    __syncthreads();
    if (j + 1 < nj) {   // overlap next-tile global loads with compute
      const int jn = j0 + 64;
      vr0 = *(const bf16x8*)(vh + (size_t)r0 * T_ + jn + g0 * 8);
      vr1 = *(const bf16x8*)(vh + (size_t)r1 * T_ + jn + g0 * 8);
      kn0 = *(const bf16x8*)(kr + (size_t)jn * HD_ + quad * 8);
      kn1 = *(const bf16x8*)(kr + (size_t)jn * HD_ + 32 + quad * 8);
    }
    // S^T = K (Q/8)^T for this wave's 16 kv rows x all 64 q (swapped MFMA)
    f32x4 ns[4] = {};
    __builtin_amdgcn_s_setprio(1);
#pragma unroll
    for (int qb = 0; qb < 4; ++qb) {
      ns[qb] = __builtin_amdgcn_mfma_f32_16x16x32_bf16(kf0, qf[qb][0], ns[qb], 0, 0, 0);
      ns[qb] = __builtin_amdgcn_mfma_f32_16x16x32_bf16(kf1, qf[qb][1], ns[qb], 0, 0, 0);
    }
    __builtin_amdgcn_s_setprio(0);
    if (j + 1 < nj) { kf0 = kn0; kf1 = kn1; }
    // causal mask (last j only): lane holds kv=j0+w16+quad*4+r, q=q0+qb*16+lr
    if (j0 + 63 > q0) {
      const int kvb = j0 + w16 + quad * 4;
#pragma unroll
      for (int qb = 0; qb < 4; ++qb) {
        const int qg = q0 + qb * 16 + lr;
#pragma unroll
        for (int r = 0; r < 4; ++r)
          if (kvb + r > qg) ns[qb][r] = -3.0e38f;
      }
    }
    // static-base softmax: P = exp(s)
#pragma unroll
    for (int qb = 0; qb < 4; ++qb)
#pragma unroll
      for (int r = 0; r < 4; ++r)
        ns[qb][r] = __expf(ns[qb][r]);
    // scatter P^T into block-shared sP: 4 kv-contiguous values -> b64 writes
#pragma unroll
    for (int qb = 0; qb < 4; ++qb) {
      bf16x4 pk;
#pragma unroll
      for (int r = 0; r < 4; ++r) pk[r] = (__bf16)ns[qb][r];
      *(bf16x4*)(&sP[pb][qb * 16 + lr][w16 + quad * 4]) = pk;
    }
    __syncthreads();   // all waves' P columns visible
    bf16x8 pf[2];
#pragma unroll
    for (int ks = 0; ks < 2; ++ks)
      pf[ks] = *(const bf16x8*)(&sP[pb][w16 + lr][ks * 32 + quad * 8]);
    // O += P * V  (V^T from LDS: row = hd, cols = kv); row sums via ones-MFMA
    __builtin_amdgcn_s_setprio(1);
#pragma unroll
    for (int ni = 0; ni < 4; ++ni) {
      const int row = ni * 16 + lr;
#pragma unroll
      for (int ks = 0; ks < 2; ++ks) {
        const int ch = (ks * 4 + quad) ^ (row & 7);
        bf16x8 vf = *(const bf16x8*)(sV + row * 64 + ch * 8);
        o[ni] = __builtin_amdgcn_mfma_f32_16x16x32_bf16(pf[ks], vf, o[ni], 0, 0, 0);
      }
    }
    ls = __builtin_amdgcn_mfma_f32_16x16x32_bf16(pf[0], onesf, ls, 0, 0, 0);
    ls = __builtin_amdgcn_mfma_f32_16x16x32_bf16(pf[1], onesf, ls, 0, 0, 0);
    __builtin_amdgcn_s_setprio(0);
  }
  // normalize and store ctx in merged [b*T+t][h*64+d] layout (bf16).
  // ls[r] = rowsum for q = q0 + w16 + quad*4 + r (replicated over lr).
#pragma unroll
  for (int r = 0; r < 4; ++r) {
    const float inv = 1.0f / ls[r];
    const int t = q0 + w16 + quad * 4 + r;
#pragma unroll
    for (int ni = 0; ni < 4; ++ni)
      ctx[((size_t)(b * T_ + t)) * D_ + h * HD_ + ni * 16 + lr] =
          (__bf16)(o[ni][r] * inv);
  }
}

// ---------------------------------------------------------------------------
extern "C" void kernel_launch(void* const* d_in, const int* in_sizes, int n_in,
                              void* d_out, int out_size, void* d_ws, size_t ws_size,
                              hipStream_t stream) {
  (void)in_sizes; (void)n_in; (void)out_size; (void)ws_size;
  const float* x  = (const float*)d_in[0];
  const float* wq = (const float*)d_in[1];
  const float* wk = (const float*)d_in[2];
  const float* wv = (const float*)d_in[3];
  const float* wo = (const float*)d_in[4];
  const float* bo = (const float*)d_in[5];
  float* outp = (float*)d_out;

  char* ws = (char*)d_ws;
  __bf16* ctx    = (__bf16*)(ws + 0);           // [4096][1024] = 8 MB
  __bf16* wqkv_t = (__bf16*)(ws + 0);           // 3072x1024 = 6 MB (dead after gemm<0>)
  __bf16* wo_t   = (__bf16*)(ws + 8388608);     // 1024x1024 = 2 MB
  __bf16* q_b    = (__bf16*)(ws + 10485760);    // [2][16][2048][64] = 8 MB
  __bf16* k_b    = (__bf16*)(ws + 18874368);    // 8 MB
  __bf16* vt_b   = (__bf16*)(ws + 27262976);    // [2][16][64][2048] = 8 MB
  __bf16* xc     = (__bf16*)(ws + 35651584);    // canonical bf16 x = 8 MB

  prep_kernel<<<8192, 256, 0, stream>>>(x, wq, wk, wv, wo, xc, wqkv_t, wo_t);
  gemm128_kernel<0><<<768, 256, 0, stream>>>(xc, wqkv_t, 1024, q_b, k_b, vt_b, nullptr, nullptr);
  attn_kernel<<<1024, 256, 0, stream>>>(q_b, k_b, vt_b, ctx);
  gemm128_kernel<1><<<256, 256, 0, stream>>>(ctx, wo_t, 1024, nullptr, nullptr, nullptr, bo, outp);
}

// Round 10
// 169.431 us; speedup vs baseline: 1.1509x; 1.0237x over previous
//
#include <hip/hip_runtime.h>
#include <hip/hip_bf16.h>
#include <stdint.h>

// Problem constants: B=2, T=2048, D=1024, H=16, HD=64
#define B_  2
#define T_  2048
#define D_  1024
#define H_  16
#define HD_ 64

typedef __bf16 bf16x8 __attribute__((ext_vector_type(8)));
typedef __bf16 bf16x4 __attribute__((ext_vector_type(4)));
typedef float  f32x4  __attribute__((ext_vector_type(4)));

__device__ __forceinline__ void async_copy16(const void* g, void* l) {
  __builtin_amdgcn_global_load_lds((__attribute__((address_space(1))) void*)(g),
                                   (__attribute__((address_space(3))) void*)(l),
                                   16, 0, 0);
}

// ---------------------------------------------------------------------------
// Fused prep v2 — R9 audit: prep was the hidden ~35-40us kernel (2B/lane
// transpose writes = 4x write amplification; scalar fp32 reads; 8192 tiny
// blocks). v2: 64x64 tiles, vector loads, 128B coalesced row writes.
//   blocks [0,1024):    transpose+convert the four 1024x1024 fp32 weights to
//                       bf16, dst[n][k]=src[k][n] (wq,wk,wv->wqkv_t; wo->wo_t)
//                       64x64 tile/block: f32x4 reads (256B/16-lane group),
//                       bf16x4 LDS staging (pitch 68, 8B-aligned), writes as
//                       16 lanes x bf16x4 = 128B contiguous per output row.
//   blocks [1024,3072): convert x fp32 -> bf16, 8 elems/thread
//                       (2x f32x4 in -> bf16x8 16B out).
// ---------------------------------------------------------------------------
__global__ void prep_kernel(const float* __restrict__ x,
                            const float* __restrict__ wq, const float* __restrict__ wk,
                            const float* __restrict__ wv, const float* __restrict__ wo,
                            __bf16* __restrict__ xc,
                            __bf16* __restrict__ wqkv_t, __bf16* __restrict__ wo_t) {
  const int id  = blockIdx.x;
  const int tid = threadIdx.x;
  if (id < 1024) {
    __shared__ __bf16 tile[64][68];                // pitch 68: 8B-aligned rows
    const int z   = id >> 8;                       // 0..3: wq,wk,wv,wo
    const int rem = id & 255;                      // 16x16 tiles of 64x64
    const int n0 = (rem & 15) * 64, k0 = (rem >> 4) * 64;
    const int kl = tid >> 4;                       // 0..15
    const int nn = (tid & 15) * 4;                 // 0,4,..,60
    const float* src = (z == 0) ? wq : (z == 1) ? wk : (z == 2) ? wv : wo;
    __bf16* dst = (z < 3) ? (wqkv_t + (size_t)z * 1024 * 1024) : wo_t;
#pragma unroll
    for (int it = 0; it < 4; ++it) {
      const int k = it * 16 + kl;
      const f32x4 v = *(const f32x4*)(src + (size_t)(k0 + k) * 1024 + n0 + nn);
      bf16x4 bv;
#pragma unroll
      for (int j = 0; j < 4; ++j) bv[j] = (__bf16)v[j];
      *(bf16x4*)&tile[k][nn] = bv;                 // 8B vector LDS write
    }
    __syncthreads();
#pragma unroll
    for (int it = 0; it < 4; ++it) {
      const int n = it * 16 + kl;                  // output row (n-index)
      bf16x4 bv;
#pragma unroll
      for (int j = 0; j < 4; ++j) bv[j] = tile[nn + j][n];
      // 16 lanes x 8B = 128B contiguous per output row
      *(bf16x4*)(dst + (size_t)(n0 + n) * 1024 + k0 + nn) = bv;
    }
  } else {
    const int i0 = ((id - 1024) * 256 + tid) * 8;
    const f32x4 f0 = *(const f32x4*)(x + i0);
    const f32x4 f1 = *(const f32x4*)(x + i0 + 4);
    bf16x8 v;
#pragma unroll
    for (int k = 0; k < 4; ++k) { v[k] = (__bf16)f0[k]; v[k + 4] = (__bf16)f1[k]; }
    *(bf16x8*)(xc + i0) = v;                       // 16B store
  }
}

// ---------------------------------------------------------------------------
// 128x128-tile bf16 MFMA GEMM, async global_load_lds staging — PROVEN (R5,
// in the 172.26us best total). T1 XCD-aware bijective grid swizzle:
//   MODE 0: grid 768; each XCD owns 3 full B-panel columns (768KB < 4MB L2).
//   MODE 1: grid 256; each XCD sees full wo_t (2MB) + A chunk.
// MODE 0 epilogue scatters Q (x0.125) / K to [b,h,t,hd], V^T to [b,h,hd,t].
// MODE 1 epilogue adds bias (fp32), stores fp32 to out.
// ---------------------------------------------------------------------------
template <int MODE>
__launch_bounds__(256)
__global__ void gemm128_kernel(const __bf16* __restrict__ A, const __bf16* __restrict__ Bt, int K,
                               __bf16* __restrict__ q_b, __bf16* __restrict__ k_b,
                               __bf16* __restrict__ vt_b,
                               const float* __restrict__ bo, float* __restrict__ outp) {
  __shared__ __align__(16) __bf16 As[128 * 64];
  __shared__ __align__(16) __bf16 Bs[128 * 64];
  const int tid  = threadIdx.x;
  const int w    = tid >> 6, lane = tid & 63;
  const int quad = lane >> 4, lr = lane & 15;

  const int orig = blockIdx.x;
  int bx, by;
  if (MODE == 0) {
    const int wgid = (orig & 7) * 96 + (orig >> 3);   // 768 blocks
    bx = wgid >> 5;            // 0..23  (N columns, 3 per XCD)
    by = wgid & 31;            // 0..31
  } else {
    const int wgid = (orig & 7) * 32 + (orig >> 3);   // 256 blocks
    bx = wgid & 7;             // 0..7
    by = wgid >> 3;            // 0..31
  }
  const int tm = by * 128, tn = bx * 128;
  const int wm = (w >> 1) * 64, wn = (w & 1) * 64;
  const int lrow   = lane >> 3;
  const int gchunk = (lane & 7) ^ lrow;

  f32x4 acc[4][4] = {};

  for (int k0 = 0; k0 < K; k0 += 64) {
#pragma unroll
    for (int c = 0; c < 4; ++c) {
      const int chunk = w * 4 + c;             // wave-uniform LDS base
      const int row   = chunk * 8 + lrow;
      async_copy16(A  + (size_t)(tm + row) * K + k0 + gchunk * 8, As + chunk * 512);
      async_copy16(Bt + (size_t)(tn + row) * K + k0 + gchunk * 8, Bs + chunk * 512);
    }
    __syncthreads();
#pragma unroll
    for (int ks = 0; ks < 2; ++ks) {
      bf16x8 af[4], bfr[4];
#pragma unroll
      for (int mi = 0; mi < 4; ++mi) {
        const int row = wm + mi * 16 + lr;
        const int ch  = (ks * 4 + quad) ^ (row & 7);
        af[mi] = *(const bf16x8*)(As + row * 64 + ch * 8);
      }
#pragma unroll
      for (int ni = 0; ni < 4; ++ni) {
        const int row = wn + ni * 16 + lr;
        const int ch  = (ks * 4 + quad) ^ (row & 7);
        bfr[ni] = *(const bf16x8*)(Bs + row * 64 + ch * 8);
      }
#pragma unroll
      for (int mi = 0; mi < 4; ++mi)
#pragma unroll
        for (int ni = 0; ni < 4; ++ni)
          acc[mi][ni] = __builtin_amdgcn_mfma_f32_16x16x32_bf16(af[mi], bfr[ni], acc[mi][ni], 0, 0, 0);
    }
    __syncthreads();
  }

  if (MODE == 0) {
#pragma unroll
    for (int mi = 0; mi < 4; ++mi) {
      const int mrow0 = tm + wm + mi * 16 + quad * 4;
      const int b  = mrow0 >> 11;
      const int t0 = mrow0 & 2047;
#pragma unroll
      for (int ni = 0; ni < 4; ++ni) {
        const int ncol = tn + wn + ni * 16 + lr;
        const int mat  = ncol >> 10;
        const int nn   = ncol & 1023;
        const int h = nn >> 6, hd = nn & 63;
        if (mat == 0) {
#pragma unroll
          for (int r = 0; r < 4; ++r)
            q_b[((size_t)((b * H_ + h) * T_ + t0 + r)) * HD_ + hd] =
                (__bf16)(acc[mi][ni][r] * 0.125f);
        } else if (mat == 1) {
#pragma unroll
          for (int r = 0; r < 4; ++r)
            k_b[((size_t)((b * H_ + h) * T_ + t0 + r)) * HD_ + hd] =
                (__bf16)(acc[mi][ni][r]);
        } else {
          bf16x4 pk;
#pragma unroll
          for (int r = 0; r < 4; ++r) pk[r] = (__bf16)(acc[mi][ni][r]);
          *(bf16x4*)(vt_b + ((size_t)(b * H_ + h) * HD_ + hd) * T_ + t0) = pk;
        }
      }
    }
  } else {
#pragma unroll
    for (int mi = 0; mi < 4; ++mi) {
      const int m0 = tm + wm + mi * 16 + quad * 4;
#pragma unroll
      for (int ni = 0; ni < 4; ++ni) {
        const int n = tn + wn + ni * 16 + lr;
        const float bias = bo[n];
#pragma unroll
        for (int r = 0; r < 4; ++r)
          outp[(size_t)(m0 + r) * D_ + n] = acc[mi][ni][r] + bias;
      }
    }
  }
}

// ---------------------------------------------------------------------------
// Flash attention v11 (causal) — EXACT R6 code (best measured total 172.26us),
// __launch_bounds__(256,3) (R9 showed occ-4 is neutral; keep best-measured).
// K-split QK^T (wave w owns keys w*16..+15, swapped-operand MFMA S^T),
// K direct-to-reg ping-pong, V staged in XOR-swizzled LDS, block-shared
// sP[2] P^T exchange with b64 writes, ones-MFMA row sums, XCD head clustering.
// ---------------------------------------------------------------------------
__launch_bounds__(256, 3)
__global__ void attn_kernel(const __bf16* __restrict__ q_b, const __bf16* __restrict__ k_b,
                            const __bf16* __restrict__ vt_b, __bf16* __restrict__ ctx) {
  __shared__ __align__(16) __bf16 sV[64 * 64];      // [hd][kv] XOR-swizzled
  __shared__ __align__(16) __bf16 sP[2][64][72];    // block-shared dbuf P^T tile
  const int tid  = threadIdx.x;
  const int w    = tid >> 6, lane = tid & 63;
  const int quad = lane >> 4, lr = lane & 15;
  const int id = blockIdx.x;
  const int bh  = (id & 7) * 4 + ((id >> 3) & 3);   // XCD-clustered head
  const int t0i = (id >> 5) & 7;                    // slot within round
  const int rnd = id >> 8;                          // round 0..3 (heavy first)
  const int tq  = (3 - rnd) * 8 + ((rnd & 1) ? t0i : (7 - t0i));
  const __bf16* qh = q_b  + (size_t)bh * T_ * HD_;
  const __bf16* kh = k_b  + (size_t)bh * T_ * HD_;
  const __bf16* vh = vt_b + (size_t)bh * HD_ * T_;
  const int b = bh >> 4, h = bh & 15;

  const int r0 = tid >> 3, r1 = (tid + 256) >> 3;   // V staging rows (0..63)
  const int g0 = tid & 7;                           // chunk-in-row

  const int q0 = tq * 64;                           // block's 64-row Q tile
  const int nj = tq + 1;
  const int w16 = w * 16;

  bf16x8 qf[4][2];
#pragma unroll
  for (int qs = 0; qs < 4; ++qs)
#pragma unroll
    for (int ks = 0; ks < 2; ++ks)
      qf[qs][ks] = *(const bf16x8*)(qh + (size_t)(q0 + qs * 16 + lr) * HD_ + ks * 32 + quad * 8);

  bf16x8 onesf;
#pragma unroll
  for (int j = 0; j < 8; ++j) onesf[j] = (__bf16)1.0f;

  f32x4 o[4] = {};
  f32x4 ls = {};

  // K slice for this wave, iter 0 (direct to regs; ping-pong prefetched)
  const __bf16* kr = kh + (size_t)(w16 + lr) * HD_;
  bf16x8 kf0 = *(const bf16x8*)(kr + quad * 8);
  bf16x8 kf1 = *(const bf16x8*)(kr + 32 + quad * 8);
  bf16x8 kn0, kn1;

  // V tile j=0 prefetch into registers
  bf16x8 vr0 = *(const bf16x8*)(vh + (size_t)r0 * T_ + g0 * 8);
  bf16x8 vr1 = *(const bf16x8*)(vh + (size_t)r1 * T_ + g0 * 8);

  for (int j = 0; j < nj; ++j) {
    const int j0 = j * 64;
    const int pb = j & 1;
    __syncthreads();   // all waves done reading sV (and sP[pb]) from prev
    *(bf16x8*)(sV + r0 * 64 + (g0 ^ (r0 & 7)) * 8) = vr0;
    *(bf16x8*)(sV + r1 * 64 + (g0 ^ (r1 & 7)) * 8) = vr1;
    __syncthreads();
    if (j + 1 < nj) {   // overlap next-tile global loads with compute
      const int jn = j0 + 64;
      vr0 = *(const bf16x8*)(vh + (size_t)r0 * T_ + jn + g0 * 8);
      vr1 = *(const bf16x8*)(vh + (size_t)r1 * T_ + jn + g0 * 8);
      kn0 = *(const bf16x8*)(kr + (size_t)jn * HD_ + quad * 8);
      kn1 = *(const bf16x8*)(kr + (size_t)jn * HD_ + 32 + quad * 8);
    }
    // S^T = K (Q/8)^T for this wave's 16 kv rows x all 64 q (swapped MFMA)
    f32x4 ns[4] = {};
    __builtin_amdgcn_s_setprio(1);
#pragma unroll
    for (int qb = 0; qb < 4; ++qb) {
      ns[qb] = __builtin_amdgcn_mfma_f32_16x16x32_bf16(kf0, qf[qb][0], ns[qb], 0, 0, 0);
      ns[qb] = __builtin_amdgcn_mfma_f32_16x16x32_bf16(kf1, qf[qb][1], ns[qb], 0, 0, 0);
    }
    __builtin_amdgcn_s_setprio(0);
    if (j + 1 < nj) { kf0 = kn0; kf1 = kn1; }
    // causal mask (last j only): lane holds kv=j0+w16+quad*4+r, q=q0+qb*16+lr
    if (j0 + 63 > q0) {
      const int kvb = j0 + w16 + quad * 4;
#pragma unroll
      for (int qb = 0; qb < 4; ++qb) {
        const int qg = q0 + qb * 16 + lr;
#pragma unroll
        for (int r = 0; r < 4; ++r)
          if (kvb + r > qg) ns[qb][r] = -3.0e38f;
      }
    }
    // static-base softmax: P = exp(s)
#pragma unroll
    for (int qb = 0; qb < 4; ++qb)
#pragma unroll
      for (int r = 0; r < 4; ++r)
        ns[qb][r] = __expf(ns[qb][r]);
    // scatter P^T into block-shared sP: 4 kv-contiguous values -> b64 writes
#pragma unroll
    for (int qb = 0; qb < 4; ++qb) {
      bf16x4 pk;
#pragma unroll
      for (int r = 0; r < 4; ++r) pk[r] = (__bf16)ns[qb][r];
      *(bf16x4*)(&sP[pb][qb * 16 + lr][w16 + quad * 4]) = pk;
    }
    __syncthreads();   // all waves' P columns visible
    bf16x8 pf[2];
#pragma unroll
    for (int ks = 0; ks < 2; ++ks)
      pf[ks] = *(const bf16x8*)(&sP[pb][w16 + lr][ks * 32 + quad * 8]);
    // O += P * V  (V^T from LDS: row = hd, cols = kv); row sums via ones-MFMA
    __builtin_amdgcn_s_setprio(1);
#pragma unroll
    for (int ni = 0; ni < 4; ++ni) {
      const int row = ni * 16 + lr;
#pragma unroll
      for (int ks = 0; ks < 2; ++ks) {
        const int ch = (ks * 4 + quad) ^ (row & 7);
        bf16x8 vf = *(const bf16x8*)(sV + row * 64 + ch * 8);
        o[ni] = __builtin_amdgcn_mfma_f32_16x16x32_bf16(pf[ks], vf, o[ni], 0, 0, 0);
      }
    }
    ls = __builtin_amdgcn_mfma_f32_16x16x32_bf16(pf[0], onesf, ls, 0, 0, 0);
    ls = __builtin_amdgcn_mfma_f32_16x16x32_bf16(pf[1], onesf, ls, 0, 0, 0);
    __builtin_amdgcn_s_setprio(0);
  }
  // normalize and store ctx in merged [b*T+t][h*64+d] layout (bf16).
  // ls[r] = rowsum for q = q0 + w16 + quad*4 + r (replicated over lr).
#pragma unroll
  for (int r = 0; r < 4; ++r) {
    const float inv = 1.0f / ls[r];
    const int t = q0 + w16 + quad * 4 + r;
#pragma unroll
    for (int ni = 0; ni < 4; ++ni)
      ctx[((size_t)(b * T_ + t)) * D_ + h * HD_ + ni * 16 + lr] =
          (__bf16)(o[ni][r] * inv);
  }
}

// ---------------------------------------------------------------------------
extern "C" void kernel_launch(void* const* d_in, const int* in_sizes, int n_in,
                              void* d_out, int out_size, void* d_ws, size_t ws_size,
                              hipStream_t stream) {
  (void)in_sizes; (void)n_in; (void)out_size; (void)ws_size;
  const float* x  = (const float*)d_in[0];
  const float* wq = (const float*)d_in[1];
  const float* wk = (const float*)d_in[2];
  const float* wv = (const float*)d_in[3];
  const float* wo = (const float*)d_in[4];
  const float* bo = (const float*)d_in[5];
  float* outp = (float*)d_out;

  char* ws = (char*)d_ws;
  __bf16* ctx    = (__bf16*)(ws + 0);           // [4096][1024] = 8 MB
  __bf16* wqkv_t = (__bf16*)(ws + 0);           // 3072x1024 = 6 MB (dead after gemm<0>)
  __bf16* wo_t   = (__bf16*)(ws + 8388608);     // 1024x1024 = 2 MB
  __bf16* q_b    = (__bf16*)(ws + 10485760);    // [2][16][2048][64] = 8 MB
  __bf16* k_b    = (__bf16*)(ws + 18874368);    // 8 MB
  __bf16* vt_b   = (__bf16*)(ws + 27262976);    // [2][16][64][2048] = 8 MB
  __bf16* xc     = (__bf16*)(ws + 35651584);    // canonical bf16 x = 8 MB

  prep_kernel<<<3072, 256, 0, stream>>>(x, wq, wk, wv, wo, xc, wqkv_t, wo_t);
  gemm128_kernel<0><<<768, 256, 0, stream>>>(xc, wqkv_t, 1024, q_b, k_b, vt_b, nullptr, nullptr);
  attn_kernel<<<1024, 256, 0, stream>>>(q_b, k_b, vt_b, ctx);
  gemm128_kernel<1><<<256, 256, 0, stream>>>(ctx, wo_t, 1024, nullptr, nullptr, nullptr, bo, outp);
}